// Round 1
// baseline (94.452 us; speedup 1.0000x reference)
//
#include <hip/hip_runtime.h>

#define NN 512

// ---------------- Kernel 1: fused per-anchor S-row dot + SmoothAP row logic ----
// 256 blocks, 2 anchors each (i = 2b, 2b+1). P is 1 MB -> L2-resident; each
// block streams all 512 rows of P once (thread t owns rows t and t+256) and
// keeps srow in LDS. Dot chains are sequential in d (ascending), bitwise
// identical to the previous tiled GEMM's accumulation order.
__global__ __launch_bounds__(256) void sap_fused(const float* __restrict__ P,
                                                 const int* __restrict__ labels,
                                                 float* __restrict__ per_anchor) {
    __shared__ __align__(16) float arow[2][NN];
    __shared__ __align__(16) float srow[2][NN];
    __shared__ __align__(16) int   labels_sh[NN];
    __shared__ float posf[NN];
    __shared__ int   poslist[NN];
    __shared__ int   npos_cnt;
    __shared__ float wave_part[4];

    const int t  = threadIdx.x;
    const int i0 = blockIdx.x * 2;

    // ---- stage the 2 anchor rows (256 float4) + labels (128 int4), coalesced
    ((float4*)&arow[0][0])[t] = ((const float4*)&P[i0 * NN])[t];
    if (t < 128) ((int4*)labels_sh)[t] = ((const int4*)labels)[t];
    __syncthreads();

    // ---- dot phase: thread t owns rows k0 = t, k1 = t + 256
    {
        const float4* B0 = (const float4*)&P[t * NN];
        const float4* B1 = (const float4*)&P[(t + 256) * NN];
        const float4* A0 = (const float4*)&arow[0][0];
        const float4* A1 = (const float4*)&arow[1][0];
        float s00 = 0.f, s01 = 0.f, s10 = 0.f, s11 = 0.f;
#pragma unroll 8
        for (int c = 0; c < NN / 4; ++c) {
            float4 b0 = B0[c];
            float4 b1 = B1[c];
            float4 a0 = A0[c];   // wave-uniform address -> LDS broadcast
            float4 a1 = A1[c];
            // four independent sequential chains, each ascending in d
            s00 += a0.x * b0.x; s00 += a0.y * b0.y; s00 += a0.z * b0.z; s00 += a0.w * b0.w;
            s01 += a1.x * b0.x; s01 += a1.y * b0.y; s01 += a1.z * b0.z; s01 += a1.w * b0.w;
            s10 += a0.x * b1.x; s10 += a0.y * b1.y; s10 += a0.z * b1.z; s10 += a0.w * b1.w;
            s11 += a1.x * b1.x; s11 += a1.y * b1.y; s11 += a1.z * b1.z; s11 += a1.w * b1.w;
        }
        srow[0][t]       = s00;
        srow[1][t]       = s01;
        srow[0][t + 256] = s10;
        srow[1][t + 256] = s11;
    }

    const int wave = t >> 6, lane = t & 63;
    // sigmoid(clip(x/T,-50,50)) = 1/(1+exp2(clip(-x*100*log2e, +-50*log2e)))
    const float C1   = 100.0f * 1.44269504088896340736f;
    const float CLIP = 50.0f  * 1.44269504088896340736f;

    for (int a = 0; a < 2; ++a) {
        const int i  = i0 + a;
        const int li = labels_sh[i];
        __syncthreads();                    // srow ready / protect reused buffers
        if (t == 0) npos_cnt = 0;
        if (t < 4) wave_part[t] = 0.f;
        __syncthreads();
        for (int k = t; k < NN; k += 256) {
            bool p  = (labels_sh[k] == li) && (k != i);
            posf[k] = p ? 1.f : 0.f;
            if (p) { int idx = atomicAdd(&npos_cnt, 1); poslist[idx] = k; }
        }
        __syncthreads();

        const int cnt = npos_cnt;           // positives excluding self
        if (cnt == 0) {                     // n_pos == 1 -> per_anchor = 0
            if (t == 0) per_anchor[i] = 0.f;
            continue;
        }

        const float* sr = srow[a];
        float acc = 0.f;                    // lane-0 accumulation per wave
        for (int idx = wave; idx <= cnt; idx += 4) {   // idx==cnt -> j==i (eye)
            const int   j   = (idx == cnt) ? i : poslist[idx];
            const float sij = sr[j];
            float sum_all = 0.f, sum_pos = 0.f;
#pragma unroll
            for (int kk = 0; kk < 8; kk++) {
                const int k = lane + (kk << 6);
                float y = (sij - sr[k]) * C1;
                y = fminf(fmaxf(y, -CLIP), CLIP);
                float tt = 1.0f / (1.0f + exp2f(y));
                if (k == j) tt = 0.f;       // (1-eye)[j,k] factor
                sum_all += tt;
                sum_pos += tt * posf[k];    // posf[i]==0 excludes k==i
            }
#pragma unroll
            for (int off = 32; off; off >>= 1) {
                sum_all += __shfl_down(sum_all, off);
                sum_pos += __shfl_down(sum_pos, off);
            }
            if (lane == 0) {
                const float den = 1.0f + sum_all;
                const float num = (j == i) ? 1.0f : (1.0f + sum_pos);
                acc += num / den;
            }
        }
        if (lane == 0) wave_part[wave] = acc;
        __syncthreads();
        if (t == 0) {
            per_anchor[i] = (wave_part[0] + wave_part[1] + wave_part[2] + wave_part[3])
                          / (float)(cnt + 1);
        }
    }
}

// ---------------- Kernel 2: final reduce --------------------------------------
__global__ __launch_bounds__(256) void sap_reduce(const float* __restrict__ per_anchor,
                                                  float* __restrict__ out) {
    __shared__ float sh[256];
    const int t = threadIdx.x;
    sh[t] = per_anchor[t] + per_anchor[t + 256];
    __syncthreads();
    for (int s = 128; s; s >>= 1) {
        if (t < s) sh[t] += sh[t + s];
        __syncthreads();
    }
    if (t == 0) out[0] = 1.0f - sh[0] / (float)NN;
}

extern "C" void kernel_launch(void* const* d_in, const int* in_sizes, int n_in,
                              void* d_out, int out_size, void* d_ws, size_t ws_size,
                              hipStream_t stream) {
    const float* preds  = (const float*)d_in[0];
    const int*   labels = (const int*)d_in[1];
    float* out        = (float*)d_out;
    float* per_anchor = (float*)d_ws;       // 512 floats

    sap_fused<<<NN / 2, 256, 0, stream>>>(preds, labels, per_anchor);
    sap_reduce<<<1, 256, 0, stream>>>(per_anchor, out);
}

// Round 2
// 73.363 us; speedup vs baseline: 1.2875x; 1.2875x over previous
//
#include <hip/hip_runtime.h>

#define NN 512

// ---------------- Kernel 1: fused per-anchor S-row dot + SmoothAP row logic ----
// 256 blocks x 512 threads, 2 anchors per block (i = 2b, 2b+1).
// Dot phase: each 16-lane group owns one row k per batch; lane g covers float4
// slots {g+16c, c=0..7} -> wave loads are 4 rows x 256B contiguous segments
// (fully coalesced, 16 lines/instr vs 64-line scatter of the previous version).
// Anchor-row operands are lane-fixed 32-float chunks held in VGPRs (no LDS
// traffic in the inner loop). Cross-lane sum: 4-level shfl_xor within the
// 16-lane group, amortized over 4 rows in flight.
__global__ __launch_bounds__(512) void sap_fused(const float* __restrict__ P,
                                                 const int* __restrict__ labels,
                                                 float* __restrict__ per_anchor) {
    __shared__ float srow[2][NN];
    __shared__ int   labels_sh[NN];
    __shared__ float posf[NN];
    __shared__ int   poslist[NN];
    __shared__ int   npos_cnt;
    __shared__ float wave_part[8];

    const int t    = threadIdx.x;          // 0..511
    const int lane = t & 63;
    const int wave = t >> 6;               // 0..7
    const int g    = lane & 15;            // lane within 16-group
    const int grp  = lane >> 4;            // 0..3: row-group within wave
    const int i0   = blockIdx.x * 2;

    if (t < 128) ((int4*)labels_sh)[t] = ((const int4*)labels)[t];

    // ---- anchor rows into registers: lane's slots are float4 indices {g+16c}
    float4 a0[8], a1[8];
    {
        const float4* A0 = (const float4*)&P[i0 * NN];
        const float4* A1 = (const float4*)&P[(i0 + 1) * NN];
#pragma unroll
        for (int c = 0; c < 8; ++c) {
            a0[c] = A0[g + 16 * c];
            a1[c] = A1[g + 16 * c];
        }
    }

    // ---- dot phase: wave w owns rows [64w, 64w+64); 4 rows in flight per batch
#pragma unroll 4
    for (int b = 0; b < 16; ++b) {
        const int k = wave * 64 + b * 4 + grp;
        const float4* B = (const float4*)&P[k * NN];
        float s0 = 0.f, s1 = 0.f;
#pragma unroll
        for (int c = 0; c < 8; ++c) {
            const float4 bb = B[g + 16 * c];
            s0 += a0[c].x * bb.x; s0 += a0[c].y * bb.y;
            s0 += a0[c].z * bb.z; s0 += a0[c].w * bb.w;
            s1 += a1[c].x * bb.x; s1 += a1[c].y * bb.y;
            s1 += a1[c].z * bb.z; s1 += a1[c].w * bb.w;
        }
#pragma unroll
        for (int off = 1; off < 16; off <<= 1) {   // stays within the 16-group
            s0 += __shfl_xor(s0, off);
            s1 += __shfl_xor(s1, off);
        }
        if (g == 0) { srow[0][k] = s0; srow[1][k] = s1; }
    }

    // ---- row phase (identical math to the verified version, 8 waves now)
    // sigmoid(clip(x/T,-50,50)) = 1/(1+exp2(clip(-x*100*log2e, +-50*log2e)))
    const float C1   = 100.0f * 1.44269504088896340736f;
    const float CLIP = 50.0f  * 1.44269504088896340736f;

    for (int a = 0; a < 2; ++a) {
        const int i = i0 + a;
        __syncthreads();                   // srow ready / protect reused buffers
        if (t == 0) npos_cnt = 0;
        if (t < 8) wave_part[t] = 0.f;
        __syncthreads();
        const int li = labels_sh[i];
        {
            bool p  = (labels_sh[t] == li) && (t != i);
            posf[t] = p ? 1.f : 0.f;
            if (p) { int idx = atomicAdd(&npos_cnt, 1); poslist[idx] = t; }
        }
        __syncthreads();

        const int cnt = npos_cnt;          // positives excluding self
        if (cnt == 0) {                    // n_pos == 1 -> per_anchor = 0
            if (t == 0) per_anchor[i] = 0.f;
            continue;
        }

        const float* sr = srow[a];
        float acc = 0.f;                   // lane-0 accumulation per wave
        for (int idx = wave; idx <= cnt; idx += 8) {   // idx==cnt -> j==i (eye)
            const int   j   = (idx == cnt) ? i : poslist[idx];
            const float sij = sr[j];
            float sum_all = 0.f, sum_pos = 0.f;
#pragma unroll
            for (int kk = 0; kk < 8; kk++) {
                const int k = lane + (kk << 6);
                float y = (sij - sr[k]) * C1;
                y = fminf(fmaxf(y, -CLIP), CLIP);
                float tt = 1.0f / (1.0f + exp2f(y));
                if (k == j) tt = 0.f;      // (1-eye)[j,k] factor
                sum_all += tt;
                sum_pos += tt * posf[k];   // posf[i]==0 excludes k==i
            }
#pragma unroll
            for (int off = 32; off; off >>= 1) {
                sum_all += __shfl_down(sum_all, off);
                sum_pos += __shfl_down(sum_pos, off);
            }
            if (lane == 0) {
                const float den = 1.0f + sum_all;
                acc += ((j == i) ? 1.0f : (1.0f + sum_pos)) / den;
            }
        }
        if (lane == 0) wave_part[wave] = acc;
        __syncthreads();
        if (t == 0) {
            float tot = 0.f;
#pragma unroll
            for (int w = 0; w < 8; ++w) tot += wave_part[w];
            per_anchor[i] = tot / (float)(cnt + 1);
        }
    }
}

// ---------------- Kernel 2: final reduce --------------------------------------
__global__ __launch_bounds__(256) void sap_reduce(const float* __restrict__ per_anchor,
                                                  float* __restrict__ out) {
    __shared__ float sh[256];
    const int t = threadIdx.x;
    sh[t] = per_anchor[t] + per_anchor[t + 256];
    __syncthreads();
    for (int s = 128; s; s >>= 1) {
        if (t < s) sh[t] += sh[t + s];
        __syncthreads();
    }
    if (t == 0) out[0] = 1.0f - sh[0] / (float)NN;
}

extern "C" void kernel_launch(void* const* d_in, const int* in_sizes, int n_in,
                              void* d_out, int out_size, void* d_ws, size_t ws_size,
                              hipStream_t stream) {
    const float* preds  = (const float*)d_in[0];
    const int*   labels = (const int*)d_in[1];
    float* out        = (float*)d_out;
    float* per_anchor = (float*)d_ws;      // 512 floats

    sap_fused<<<NN / 2, 512, 0, stream>>>(preds, labels, per_anchor);
    sap_reduce<<<1, 256, 0, stream>>>(per_anchor, out);
}